// Round 1
// baseline (523.537 us; speedup 1.0000x reference)
//
#include <hip/hip_runtime.h>
#include <hip/hip_bf16.h>

typedef __bf16 bf16_t;
typedef __bf16 bf16x8 __attribute__((ext_vector_type(8)));
typedef __bf16 bf16x4 __attribute__((ext_vector_type(4)));
typedef float f32x4 __attribute__((ext_vector_type(4)));

#define B_ 16
#define T_ 128
#define H_ 512
#define L_ 2
#define V_ 32000
#define G_ 2048   /* 4*H */
#define M_ 2048   /* B*T */

#define BM 128
#define BN 128
#define BK 32

// ---------------- fp32 -> bf16 convert, 4 elems/thread ----------------
__global__ __launch_bounds__(256) void cvt_bf16(const float* __restrict__ in,
                                                bf16_t* __restrict__ out) {
    int idx = blockIdx.x * 256 + threadIdx.x;
    float4 v = ((const float4*)in)[idx];
    bf16x4 o;
    o[0] = (bf16_t)v.x; o[1] = (bf16_t)v.y; o[2] = (bf16_t)v.z; o[3] = (bf16_t)v.w;
    ((bf16x4*)out)[idx] = o;
}

// ---------------- x = relu(embedding[tokens]) -> bf16 ----------------
// tokens[b][t] = (t==0) ? BOS(1) : target[b][t-1]
__global__ __launch_bounds__(256) void embed_relu(const float* __restrict__ emb,
                                                  const int* __restrict__ target,
                                                  bf16_t* __restrict__ x) {
    int idx = blockIdx.x * 256 + threadIdx.x;   // over M_*(H_/4)
    int m  = idx >> 7;            // H_/4 = 128 vec4 per row
    int h4 = (idx & 127) << 2;
    int b = m >> 7, t = m & 127;
    int tok = (t == 0) ? 1 : target[b * T_ + t - 1];
    float4 v = *(const float4*)(emb + (size_t)tok * H_ + h4);
    bf16x4 o;
    o[0] = (bf16_t)fmaxf(v.x, 0.f);
    o[1] = (bf16_t)fmaxf(v.y, 0.f);
    o[2] = (bf16_t)fmaxf(v.z, 0.f);
    o[3] = (bf16_t)fmaxf(v.w, 0.f);
    *(bf16x4*)(x + (size_t)m * H_ + h4) = o;
}

// ---------------- biasall[l][b][g] = b_ih+b_hh+h0[b]@W_hh[g] ----------------
__global__ __launch_bounds__(256) void hproj_kernel(const float* __restrict__ enc_h,
                                                    const float* __restrict__ W_hh,
                                                    const float* __restrict__ b_ih,
                                                    const float* __restrict__ b_hh,
                                                    float* __restrict__ biasall) {
    int idx = blockIdx.x * 256 + threadIdx.x;   // L_*G_*B_ = 65536
    int b = idx & 15;
    int g = (idx >> 4) & (G_ - 1);
    int l = idx >> 15;
    const float* hrow = enc_h + ((size_t)l * B_ + b) * H_;
    const float* wrow = W_hh + ((size_t)l * G_ + g) * H_;
    float acc = b_ih[l * G_ + g] + b_hh[l * G_ + g];
    #pragma unroll 4
    for (int k = 0; k < H_; k += 4) {
        float4 hv = *(const float4*)(hrow + k);
        float4 wv = *(const float4*)(wrow + k);
        acc += hv.x * wv.x + hv.y * wv.y + hv.z * wv.z + hv.w * wv.w;
    }
    biasall[((size_t)l * B_ + b) * G_ + g] = acc;
}

// ---------------- bf16 GEMM:  C(MxN) = A(MxK) @ B(NxK)^T + bias ----------------
// bias_mode 0: bias[col]   (logits, b_out)
// bias_mode 1: bias[(tileM/128)*N + col]  (gates; M-tile == batch row since BM==T_)
__global__ __launch_bounds__(256) void gemm_bt(const bf16_t* __restrict__ A,
                                               const bf16_t* __restrict__ B,
                                               float* __restrict__ C,
                                               const float* __restrict__ bias,
                                               int M, int N, int K, int bias_mode) {
    __shared__ __align__(16) bf16_t As[BM * BK];
    __shared__ __align__(16) bf16_t Bs[BN * BK];

    const int tid  = threadIdx.x;
    const int lane = tid & 63;
    const int wave = tid >> 6;
    const int wm = wave >> 1, wn = wave & 1;
    const int quad = lane >> 4;
    const int r16  = lane & 15;

    const int tileM = blockIdx.x * BM;   // consecutive blocks share B row-block (L2)
    const int tileN = blockIdx.y * BN;

    const int srow = lane >> 2;          // 0..15 rows per wave per stage call
    const int scol = (lane & 3) * 8;     // bf16 elems (16B per lane)

    f32x4 acc[4][4];
    #pragma unroll
    for (int i = 0; i < 4; i++)
        #pragma unroll
        for (int j = 0; j < 4; j++) acc[i][j] = (f32x4){0.f, 0.f, 0.f, 0.f};

    const int nk = K / BK;
    for (int kt = 0; kt < nk; ++kt) {
        const int k0 = kt * BK;
        #pragma unroll
        for (int j = 0; j < 2; ++j) {
            const int r0 = j * 64 + wave * 16;
            const bf16_t* ga = A + (size_t)(tileM + r0 + srow) * K + k0 + scol;
            const bf16_t* gb = B + (size_t)(tileN + r0 + srow) * K + k0 + scol;
            __builtin_amdgcn_global_load_lds(
                (const __attribute__((address_space(1))) void*)ga,
                (__attribute__((address_space(3))) void*)(As + r0 * BK), 16, 0, 0);
            __builtin_amdgcn_global_load_lds(
                (const __attribute__((address_space(1))) void*)gb,
                (__attribute__((address_space(3))) void*)(Bs + r0 * BK), 16, 0, 0);
        }
        __syncthreads();

        bf16x8 af[4], bfr[4];
        #pragma unroll
        for (int mi = 0; mi < 4; mi++)
            af[mi] = *(const bf16x8*)(As + (wm * 64 + mi * 16 + r16) * BK + quad * 8);
        #pragma unroll
        for (int ni = 0; ni < 4; ni++)
            bfr[ni] = *(const bf16x8*)(Bs + (wn * 64 + ni * 16 + r16) * BK + quad * 8);
        #pragma unroll
        for (int mi = 0; mi < 4; mi++)
            #pragma unroll
            for (int ni = 0; ni < 4; ni++)
                acc[mi][ni] = __builtin_amdgcn_mfma_f32_16x16x32_bf16(
                    af[mi], bfr[ni], acc[mi][ni], 0, 0, 0);
        __syncthreads();
    }

    const float* brow = bias_mode ? (bias + (size_t)blockIdx.x * N) : bias;
    #pragma unroll
    for (int mi = 0; mi < 4; mi++) {
        #pragma unroll
        for (int ni = 0; ni < 4; ni++) {
            const int col = tileN + wn * 64 + ni * 16 + r16;
            const float bv = brow[col];
            #pragma unroll
            for (int rr = 0; rr < 4; rr++) {
                const int row = tileM + wm * 64 + mi * 16 + quad * 4 + rr;
                C[(size_t)row * N + col] = acc[mi][ni][rr] + bv;
            }
        }
    }
}

// ---------------- LSTM pointwise cell ----------------
__device__ __forceinline__ float sigf(float x) { return 1.f / (1.f + __expf(-x)); }
__device__ __forceinline__ float tanhf_(float x) { return 2.f / (1.f + __expf(-2.f * x)) - 1.f; }

__global__ __launch_bounds__(256) void lstm_cell(const float* __restrict__ gates,
                                                 const float* __restrict__ enc_c,
                                                 bf16_t* __restrict__ x,
                                                 float* __restrict__ out_h,
                                                 float* __restrict__ out_c,
                                                 int l) {
    int idx = blockIdx.x * 256 + threadIdx.x;   // M_*H_
    int m  = idx >> 9;
    int hh = idx & (H_ - 1);
    int b = m >> 7, t = m & 127;
    const float* grow = gates + (size_t)m * G_;
    float gi = grow[hh];
    float gf = grow[H_ + hh];
    float gg = grow[2 * H_ + hh];
    float go = grow[3 * H_ + hh];
    float c0 = enc_c[((size_t)l * B_ + b) * H_ + hh];
    float c = sigf(gf) * c0 + sigf(gi) * tanhf_(gg);
    float h = sigf(go) * tanhf_(c);
    x[idx] = (bf16_t)h;
    if (t == T_ - 1) {
        out_h[((size_t)l * B_ + b) * H_ + hh] = h;
        out_c[((size_t)l * B_ + b) * H_ + hh] = c;
    }
}

extern "C" void kernel_launch(void* const* d_in, const int* in_sizes, int n_in,
                              void* d_out, int out_size, void* d_ws, size_t ws_size,
                              hipStream_t stream) {
    const float* enc_h  = (const float*)d_in[1];
    const float* enc_c  = (const float*)d_in[2];
    const int*   target = (const int*)d_in[3];
    const float* emb    = (const float*)d_in[4];
    const float* W_ih   = (const float*)d_in[5];
    const float* W_hh   = (const float*)d_in[6];
    const float* b_ih   = (const float*)d_in[7];
    const float* b_hh   = (const float*)d_in[8];
    const float* W_out  = (const float*)d_in[9];
    const float* b_out  = (const float*)d_in[10];
    float* out = (float*)d_out;

    // workspace layout (bytes)
    char* w = (char*)d_ws;
    bf16_t* x       = (bf16_t*)(w);                         // 2048*512*2    = 2 MB
    bf16_t* wih_b   = (bf16_t*)(w + 2097152);               // 2*2048*512*2  = 4 MB
    bf16_t* wout_b  = (bf16_t*)(w + 6291456);               // 32000*512*2   = 32.75 MB
    float*  gates   = (float*)(w + 39059456);               // 2048*2048*4   = 16 MB
    float*  biasall = (float*)(w + 55836672);               // 2*16*2048*4   = 256 KB

    float* out_h = out + (size_t)M_ * V_;
    float* out_c = out_h + (size_t)L_ * B_ * H_;

    // 1) weight conversions
    cvt_bf16<<<(L_ * G_ * H_) / 1024, 256, 0, stream>>>(W_ih, wih_b);
    cvt_bf16<<<(V_ * H_) / 1024, 256, 0, stream>>>(W_out, wout_b);
    // 2) embedding gather + relu -> bf16
    embed_relu<<<(M_ * H_ / 4) / 256, 256, 0, stream>>>(emb, target, x);
    // 3) fused bias table: b_ih + b_hh + h0 @ W_hh^T   (both layers)
    hproj_kernel<<<(L_ * G_ * B_) / 256, 256, 0, stream>>>(enc_h, W_hh, b_ih, b_hh, biasall);

    // 4) two LSTM layers
    for (int l = 0; l < L_; ++l) {
        dim3 gg(M_ / BM, G_ / BN);
        gemm_bt<<<gg, 256, 0, stream>>>(x, wih_b + (size_t)l * G_ * H_, gates,
                                        biasall + (size_t)l * B_ * G_, M_, G_, H_, 1);
        lstm_cell<<<(M_ * H_) / 256, 256, 0, stream>>>(gates, enc_c, x, out_h, out_c, l);
    }

    // 5) logits = x @ W_out^T + b_out
    dim3 gl(M_ / BM, V_ / BN);
    gemm_bt<<<gl, 256, 0, stream>>>(x, wout_b, out, b_out, M_, V_, H_, 0);
}